// Round 5
// baseline (268.859 us; speedup 1.0000x reference)
//
#include <hip/hip_runtime.h>
#include <math.h>

#define NROWS 8192
#define DDIM 128

typedef unsigned short u16;
typedef unsigned int u32;
typedef unsigned long long u64;
typedef __attribute__((ext_vector_type(4))) float f32x4;
typedef __attribute__((ext_vector_type(2))) float f32x2;
typedef __attribute__((ext_vector_type(4))) int i32x4;
typedef __attribute__((ext_vector_type(8))) short short8;

__device__ __forceinline__ u16 f32_to_bf16(float f){
  u32 u = __float_as_uint(f);
  u32 r = (u + 0x7FFFu + ((u >> 16) & 1u)) >> 16;
  return (u16)r;
}
__device__ __forceinline__ float bf16_to_f32(u16 h){ return __uint_as_float(((u32)h) << 16); }

// ---------------- kernel 1: split f32 -> bf16 hi/lo, packed in MFMA-fragment order ----------------
__global__ __launch_bounds__(256) void pack_kernel(const float* __restrict__ in,
                                                   u16* __restrict__ phi, u16* __restrict__ plo,
                                                   float* __restrict__ sq){
  int t = blockIdx.x * 256 + threadIdx.x;
  int r = t >> 4, s = t & 15;                  // row, 8-elem segment
  const float* src = in + (size_t)r * DDIM + s * 8;
  f32x4 a = *(const f32x4*)(src);
  f32x4 b = *(const f32x4*)(src + 4);
  float x[8] = {a.x, a.y, a.z, a.w, b.x, b.y, b.z, b.w};
  short8 hv, lv;
  float ss = 0.f;
  #pragma unroll
  for (int j = 0; j < 8; ++j){
    u16 h = f32_to_bf16(x[j]);
    u16 l = f32_to_bf16(x[j] - bf16_to_f32(h));
    hv[j] = (short)h; lv[j] = (short)l;
    ss += x[j] * x[j];
  }
  size_t dst = (((size_t)(r >> 4) * 4 + (s >> 2)) * 64 + (s & 3) * 16 + (r & 15)) * 8;
  *(short8*)(phi + dst) = hv;
  *(short8*)(plo + dst) = lv;
  #pragma unroll
  for (int m = 1; m < 16; m <<= 1) ss += __shfl_xor(ss, m, 64);
  if (s == 0) sq[r] = ss;
}

// ---------------- kernel 2: triangular MFMA distance, write tile + LDS-transposed tile ----------------
__global__ __launch_bounds__(256, 2) void dist_kernel(
    const u16* __restrict__ phi, const u16* __restrict__ plo,
    const float* __restrict__ sq, const int* __restrict__ tgt,
    float* __restrict__ dist, u64* __restrict__ pos_key, u64* __restrict__ neg_key)
{
  __shared__ float ldsC[128 * 129];   // dd tile, pad 129 (129 % 32 == 1 -> conflict-free col reads)
  __shared__ int s_trow[128];         // targets of the bi-panel rows

  // XCD-aware swizzle over 2080 = 8*260 triangle blocks, then triangular decode
  int id = blockIdx.x;
  int swz = (id & 7) * 260 + (id >> 3);
  int bi = (int)((129.0 - sqrt(16641.0 - 8.0 * (double)swz)) * 0.5);
  bi = bi < 0 ? 0 : (bi > 63 ? 63 : bi);
  int tbase = bi * 64 - (bi * (bi - 1)) / 2;
  while (swz < tbase) { --bi; tbase = bi * 64 - (bi * (bi - 1)) / 2; }
  while (swz >= tbase + (64 - bi)) { tbase += (64 - bi); ++bi; }
  const int bj = bi + (swz - tbase);   // bi <= bj

  const int tid = threadIdx.x;
  if (tid < 128) s_trow[tid] = tgt[bi * 128 + tid];

  const int w = tid >> 6, lane = tid & 63;
  const int wr = w >> 1, wc = w & 1;           // 2x2 waves, each owns 64x64 output
  const int lr = lane & 15, g = lane >> 4;

  // acc[m][n] = mfma(B_frag, A_frag):
  //   row = bi*128 + wr*64 + m*16 + lr     col = bj*128 + wc*64 + n*16 + g*4 + r
  f32x4 acc[4][4] = {};

  #pragma unroll
  for (int kk = 0; kk < 4; ++kk){
    short8 ah[4], al[4], bh[4], bl[4];
    #pragma unroll
    for (int m = 0; m < 4; ++m){
      size_t offA = ((size_t)(((bi * 8 + wr * 4 + m) * 4 + kk) * 64) + lane) * 8;
      ah[m] = *(const short8*)(phi + offA);
      al[m] = *(const short8*)(plo + offA);
      size_t offB = ((size_t)(((bj * 8 + wc * 4 + m) * 4 + kk) * 64) + lane) * 8;
      bh[m] = *(const short8*)(phi + offB);
      bl[m] = *(const short8*)(plo + offB);
    }
    #pragma unroll
    for (int m = 0; m < 4; ++m)
      #pragma unroll
      for (int n = 0; n < 4; ++n){
        acc[m][n] = __builtin_amdgcn_mfma_f32_16x16x32_bf16(bh[n], ah[m], acc[m][n], 0, 0, 0);
        acc[m][n] = __builtin_amdgcn_mfma_f32_16x16x32_bf16(bl[n], ah[m], acc[m][n], 0, 0, 0);
        acc[m][n] = __builtin_amdgcn_mfma_f32_16x16x32_bf16(bh[n], al[m], acc[m][n], 0, 0, 0);
      }
  }

  // ---- phase A: direct tile -> dist + row mining + stash dd in LDS ----
  f32x4 sqc[4]; i32x4 tcv[4]; int cbase[4];
  #pragma unroll
  for (int n = 0; n < 4; ++n){
    cbase[n] = bj * 128 + wc * 64 + n * 16 + g * 4;
    sqc[n] = *(const f32x4*)(sq + cbase[n]);
    tcv[n] = *(const i32x4*)(tgt + cbase[n]);
  }
  #pragma unroll
  for (int m = 0; m < 4; ++m){
    const int row128 = wr * 64 + m * 16 + lr;
    const int grow = bi * 128 + row128;
    const float sqr = sq[grow];
    const int tr = tgt[grow];
    float bpv = -1.f, bnv = 3.0e38f; int bpc = 0x7FFFFFFF, bnc = 0x7FFFFFFF;
    float* drow = dist + (size_t)grow * NROWS;
    float* lrow = ldsC + row128 * 129;
    #pragma unroll
    for (int n = 0; n < 4; ++n){
      const int col128 = wc * 64 + n * 16 + g * 4;
      f32x4 dd4;
      #pragma unroll
      for (int r = 0; r < 4; ++r){
        float d2 = sqr + sqc[n][r] - 2.f * acc[m][n][r];
        d2 = fminf(fmaxf(d2, 1e-12f), 1e12f);
        float dd = sqrtf(d2);
        dd4[r] = dd;
        lrow[col128 + r] = dd;
        if (tr == tcv[n][r]){
          if (dd > bpv){ bpv = dd; bpc = cbase[n] + r; }
        } else {
          if (dd < bnv){ bnv = dd; bnc = cbase[n] + r; }
        }
      }
      // dist base is out+2 (8B-aligned) -> two 8B stores
      *(f32x2*)(drow + cbase[n])     = f32x2{dd4.x, dd4.y};
      *(f32x2*)(drow + cbase[n] + 2) = f32x2{dd4.z, dd4.w};
    }
    // reduce across the 4 g-groups (lanes lr, lr+16, lr+32, lr+48 hold the same row)
    #pragma unroll
    for (int msk = 16; msk <= 32; msk <<= 1){
      float ov = __shfl_xor(bpv, msk, 64); int oc = __shfl_xor(bpc, msk, 64);
      if (ov > bpv || (ov == bpv && oc < bpc)){ bpv = ov; bpc = oc; }
      ov = __shfl_xor(bnv, msk, 64); oc = __shfl_xor(bnc, msk, 64);
      if (ov < bnv || (ov == bnv && oc < bnc)){ bnv = ov; bnc = oc; }
    }
    if (g == 0){
      if (bpv >= 0.f)
        atomicMax(&pos_key[grow],
                  ((u64)__float_as_uint(bpv) << 32) | (u64)(0xFFFFFFFFu - (u32)bpc));
      if (bnv < 3.0e38f)
        atomicMin(&neg_key[grow],
                  ((u64)__float_as_uint(bnv) << 32) | (u64)(u32)bnc);
    }
  }

  __syncthreads();

  // ---- phase B: transposed tile -> dist rows of bj-panel + mining (skip on diagonal) ----
  if (bi != bj){
    const int c = tid >> 1, half = tid & 1;    // 2 threads per output row
    const int orow = bj * 128 + c;
    const int tc = tgt[orow];
    float bpv = -1.f, bnv = 3.0e38f; int bpc = 0x7FFFFFFF, bnc = 0x7FFFFFFF;
    float* drow = dist + (size_t)orow * NROWS + bi * 128 + half * 64;
    const int r0base = half * 64;
    #pragma unroll 8
    for (int i = 0; i < 64; i += 2){
      int r0 = r0base + i;
      float d0 = ldsC[(r0)     * 129 + c];
      float d1 = ldsC[(r0 + 1) * 129 + c];
      *(f32x2*)(drow + i) = f32x2{d0, d1};
      int gc0 = bi * 128 + r0;
      int t0 = s_trow[r0], t1 = s_trow[r0 + 1];
      if (t0 == tc){ if (d0 > bpv){ bpv = d0; bpc = gc0; } }
      else         { if (d0 < bnv){ bnv = d0; bnc = gc0; } }
      if (t1 == tc){ if (d1 > bpv){ bpv = d1; bpc = gc0 + 1; } }
      else         { if (d1 < bnv){ bnv = d1; bnc = gc0 + 1; } }
    }
    // combine the two halves (partner thread differs in bit 0 -> shfl_xor mask 1)
    float ov = __shfl_xor(bpv, 1, 64); int oc = __shfl_xor(bpc, 1, 64);
    if (ov > bpv || (ov == bpv && oc < bpc)){ bpv = ov; bpc = oc; }
    ov = __shfl_xor(bnv, 1, 64); oc = __shfl_xor(bnc, 1, 64);
    if (ov < bnv || (ov == bnv && oc < bnc)){ bnv = ov; bnc = oc; }
    if (half == 0){
      if (bpv >= 0.f)
        atomicMax(&pos_key[orow],
                  ((u64)__float_as_uint(bpv) << 32) | (u64)(0xFFFFFFFFu - (u32)bpc));
      if (bnv < 3.0e38f)
        atomicMin(&neg_key[orow],
                  ((u64)__float_as_uint(bnv) << 32) | (u64)(u32)bnc);
    }
  }
}

// ---------------- kernel 3: decode packed keys ----------------
__global__ __launch_bounds__(256) void decode_kernel(const u64* __restrict__ pk, const u64* __restrict__ nk,
                                                     float* __restrict__ ap, float* __restrict__ an,
                                                     int* __restrict__ p2, int* __restrict__ n1){
  int i = blockIdx.x * 256 + threadIdx.x;
  u64 p = pk[i], q = nk[i];
  ap[i] = __uint_as_float((u32)(p >> 32));
  p2[i] = (int)(0xFFFFFFFFu - (u32)(p & 0xFFFFFFFFu));
  an[i] = __uint_as_float((u32)(q >> 32));
  n1[i] = (int)(u32)(q & 0xFFFFFFFFu);
}

// ---------------- kernel 4: gathers + hinge losses + prec (deterministic single block) ----------------
__global__ __launch_bounds__(256) void final_kernel(const float* __restrict__ ap, const float* __restrict__ an,
                                                    const int* __restrict__ p2, const int* __restrict__ n1,
                                                    float* __restrict__ out){
  __shared__ float r1[256], r2[256], r3[256]; __shared__ int r4[256];
  int tid = threadIdx.x;
  float s1 = 0.f, s2 = 0.f, s3 = 0.f; int pc = 0;
  for (int i = tid; i < NROWS; i += 256){
    float a = ap[i], b = an[i];
    float n12 = an[n1[i]];
    float p12 = ap[p2[i]];
    s1 += fmaxf(a - b, 0.f);
    s2 += fmaxf(a - n12, 0.f);
    s3 += fmaxf(p12 - b, 0.f);
    pc += (b > a) ? 1 : 0;
  }
  r1[tid] = s1; r2[tid] = s2; r3[tid] = s3; r4[tid] = pc;
  __syncthreads();
  for (int s = 128; s > 0; s >>= 1){
    if (tid < s){ r1[tid] += r1[tid + s]; r2[tid] += r2[tid + s]; r3[tid] += r3[tid + s]; r4[tid] += r4[tid + s]; }
    __syncthreads();
  }
  if (tid == 0){
    float inv = 1.f / (float)NROWS;
    out[0] = r1[0] * inv + 0.1f * (r2[0] * inv) + 0.1f * (r3[0] * inv);
    out[1] = (float)r4[0] * inv;
  }
}

extern "C" void kernel_launch(void* const* d_in, const int* in_sizes, int n_in,
                              void* d_out, int out_size, void* d_ws, size_t ws_size,
                              hipStream_t stream){
  const float* inputs = (const float*)d_in[0];
  const int* targets = (const int*)d_in[1];
  float* out = (float*)d_out;
  char* ws = (char*)d_ws;

  u16* phi = (u16*)ws;                                   // 2 MiB packed hi
  u16* plo = (u16*)(ws + (2u << 20));                    // 2 MiB packed lo
  float* sq = (float*)(ws + (4u << 20));                 // 32 KiB
  u64* pos_key = (u64*)(ws + (4u << 20) + (64u << 10));  // 64 KiB
  u64* neg_key = (u64*)(ws + (4u << 20) + (128u << 10)); // 64 KiB
  float* ap = (float*)(ws + (4u << 20) + (192u << 10));
  float* an = (float*)(ws + (4u << 20) + (224u << 10));
  int* p2 = (int*)(ws + (4u << 20) + (256u << 10));
  int* n1 = (int*)(ws + (4u << 20) + (288u << 10));

  hipMemsetAsync(pos_key, 0x00, NROWS * sizeof(u64), stream);
  hipMemsetAsync(neg_key, 0xFF, NROWS * sizeof(u64), stream);

  pack_kernel<<<(NROWS * 16) / 256, 256, 0, stream>>>(inputs, phi, plo, sq);
  dist_kernel<<<2080, 256, 0, stream>>>(phi, plo, sq, targets, out + 2, pos_key, neg_key);
  decode_kernel<<<NROWS / 256, 256, 0, stream>>>(pos_key, neg_key, ap, an, p2, n1);
  final_kernel<<<1, 256, 0, stream>>>(ap, an, p2, n1, out);
}

// Round 6
// 166.257 us; speedup vs baseline: 1.6171x; 1.6171x over previous
//
#include <hip/hip_runtime.h>

#define NROWS 8192
#define DDIM 128

typedef unsigned short u16;
typedef unsigned int u32;
typedef unsigned long long u64;
typedef __attribute__((ext_vector_type(4))) float f32x4;
typedef __attribute__((ext_vector_type(2))) float f32x2;
typedef __attribute__((ext_vector_type(4))) int i32x4;
typedef __attribute__((ext_vector_type(8))) short short8;

__device__ __forceinline__ u16 f32_to_bf16(float f){
  u32 u = __float_as_uint(f);
  u32 r = (u + 0x7FFFu + ((u >> 16) & 1u)) >> 16;
  return (u16)r;
}
__device__ __forceinline__ float bf16_to_f32(u16 h){ return __uint_as_float(((u32)h) << 16); }

// ---------------- kernel 1: split f32 -> bf16 hi/lo, packed in MFMA-fragment order ----------------
__global__ __launch_bounds__(256) void pack_kernel(const float* __restrict__ in,
                                                   u16* __restrict__ phi, u16* __restrict__ plo,
                                                   float* __restrict__ sq){
  int t = blockIdx.x * 256 + threadIdx.x;
  int r = t >> 4, s = t & 15;                  // row, 8-elem segment
  const float* src = in + (size_t)r * DDIM + s * 8;
  f32x4 a = *(const f32x4*)(src);
  f32x4 b = *(const f32x4*)(src + 4);
  float x[8] = {a.x, a.y, a.z, a.w, b.x, b.y, b.z, b.w};
  short8 hv, lv;
  float ss = 0.f;
  #pragma unroll
  for (int j = 0; j < 8; ++j){
    u16 h = f32_to_bf16(x[j]);
    u16 l = f32_to_bf16(x[j] - bf16_to_f32(h));
    hv[j] = (short)h; lv[j] = (short)l;
    ss += x[j] * x[j];
  }
  size_t dst = (((size_t)(r >> 4) * 4 + (s >> 2)) * 64 + (s & 3) * 16 + (r & 15)) * 8;
  *(short8*)(phi + dst) = hv;
  *(short8*)(plo + dst) = lv;
  #pragma unroll
  for (int m = 1; m < 16; m <<= 1) ss += __shfl_xor(ss, m, 64);
  if (s == 0) sq[r] = ss;
}

// ---------------- kernel 2: LDS-free MFMA distance + fused mining, 8 waves x (64x32) ----------------
__global__ __launch_bounds__(512, 4) void dist_kernel(
    const u16* __restrict__ phi, const u16* __restrict__ plo,
    const float* __restrict__ sq, const int* __restrict__ tgt,
    float* __restrict__ dist, u64* __restrict__ pos_key, u64* __restrict__ neg_key)
{
  int id = blockIdx.x;
  int swz = (id & 7) * 512 + (id >> 3);
  const int bi = swz >> 6, bj = swz & 63;

  const int tid = threadIdx.x;
  const int w = tid >> 6, lane = tid & 63;
  const int wr = w >> 1, wc = w & 1;           // 4x2 waves; wave tile = 32 rows x 64 cols
  const int lr = lane & 15, g = lane >> 4;

  // acc[m][n] = mfma(B_frag, A_frag):
  //   row = bi*128 + wr*32 + m*16 + lr      (m = 0..1)
  //   col = bj*128 + wc*64 + n*16 + g*4 + r (n = 0..3, reg r)
  f32x4 acc[2][4] = {};

  #pragma unroll
  for (int kk = 0; kk < 4; ++kk){
    short8 ah[2], al[2], bh[4], bl[4];
    #pragma unroll
    for (int m = 0; m < 2; ++m){
      size_t offA = ((size_t)(((bi * 8 + wr * 2 + m) * 4 + kk) * 64) + lane) * 8;
      ah[m] = *(const short8*)(phi + offA);
      al[m] = *(const short8*)(plo + offA);
    }
    #pragma unroll
    for (int n = 0; n < 4; ++n){
      size_t offB = ((size_t)(((bj * 8 + wc * 4 + n) * 4 + kk) * 64) + lane) * 8;
      bh[n] = *(const short8*)(phi + offB);
      bl[n] = *(const short8*)(plo + offB);
    }
    #pragma unroll
    for (int m = 0; m < 2; ++m)
      #pragma unroll
      for (int n = 0; n < 4; ++n){
        acc[m][n] = __builtin_amdgcn_mfma_f32_16x16x32_bf16(bh[n], ah[m], acc[m][n], 0, 0, 0);
        acc[m][n] = __builtin_amdgcn_mfma_f32_16x16x32_bf16(bl[n], ah[m], acc[m][n], 0, 0, 0);
        acc[m][n] = __builtin_amdgcn_mfma_f32_16x16x32_bf16(bh[n], al[m], acc[m][n], 0, 0, 0);
      }
  }

  // ---- epilogue: d2 -> dist (sqrt only feeds stores), mining on d2 (monotone) ----
  f32x4 sqc[4]; i32x4 tcv[4]; int cbase[4];
  #pragma unroll
  for (int n = 0; n < 4; ++n){
    cbase[n] = bj * 128 + wc * 64 + n * 16 + g * 4;
    sqc[n] = *(const f32x4*)(sq + cbase[n]);
    tcv[n] = *(const i32x4*)(tgt + cbase[n]);
  }
  #pragma unroll
  for (int m = 0; m < 2; ++m){
    const int grow = bi * 128 + wr * 32 + m * 16 + lr;
    const float sqr = sq[grow];
    const int tr = tgt[grow];
    float bpv = -1.f, bnv = 3.0e38f; int bpc = 0x7FFFFFFF, bnc = 0x7FFFFFFF;
    float* drow = dist + (size_t)grow * NROWS;
    #pragma unroll
    for (int n = 0; n < 4; ++n){
      f32x4 dd4;
      #pragma unroll
      for (int r = 0; r < 4; ++r){
        float d2 = sqr + sqc[n][r] - 2.f * acc[m][n][r];
        d2 = fminf(fmaxf(d2, 1e-12f), 1e12f);
        dd4[r] = sqrtf(d2);
        if (tr == tcv[n][r]){
          if (d2 > bpv){ bpv = d2; bpc = cbase[n] + r; }
        } else {
          if (d2 < bnv){ bnv = d2; bnc = cbase[n] + r; }
        }
      }
      // dist base is out+2 (8B-aligned) -> two 8B stores
      *(f32x2*)(drow + cbase[n])     = f32x2{dd4.x, dd4.y};
      *(f32x2*)(drow + cbase[n] + 2) = f32x2{dd4.z, dd4.w};
    }
    // reduce across the 4 g-groups (lanes lr, lr+16, lr+32, lr+48 hold the same row)
    #pragma unroll
    for (int msk = 16; msk <= 32; msk <<= 1){
      float ov = __shfl_xor(bpv, msk, 64); int oc = __shfl_xor(bpc, msk, 64);
      if (ov > bpv || (ov == bpv && oc < bpc)){ bpv = ov; bpc = oc; }
      ov = __shfl_xor(bnv, msk, 64); oc = __shfl_xor(bnc, msk, 64);
      if (ov < bnv || (ov == bnv && oc < bnc)){ bnv = ov; bnc = oc; }
    }
    if (g == 0){
      if (bpv >= 0.f)
        atomicMax(&pos_key[grow],
                  ((u64)__float_as_uint(sqrtf(bpv)) << 32) | (u64)(0xFFFFFFFFu - (u32)bpc));
      if (bnv < 3.0e38f)
        atomicMin(&neg_key[grow],
                  ((u64)__float_as_uint(sqrtf(bnv)) << 32) | (u64)(u32)bnc);
    }
  }
}

// ---------------- kernel 3: decode packed keys ----------------
__global__ __launch_bounds__(256) void decode_kernel(const u64* __restrict__ pk, const u64* __restrict__ nk,
                                                     float* __restrict__ ap, float* __restrict__ an,
                                                     int* __restrict__ p2, int* __restrict__ n1){
  int i = blockIdx.x * 256 + threadIdx.x;
  u64 p = pk[i], q = nk[i];
  ap[i] = __uint_as_float((u32)(p >> 32));
  p2[i] = (int)(0xFFFFFFFFu - (u32)(p & 0xFFFFFFFFu));
  an[i] = __uint_as_float((u32)(q >> 32));
  n1[i] = (int)(u32)(q & 0xFFFFFFFFu);
}

// ---------------- kernel 4: gathers + hinge losses + prec (deterministic single block) ----------------
__global__ __launch_bounds__(256) void final_kernel(const float* __restrict__ ap, const float* __restrict__ an,
                                                    const int* __restrict__ p2, const int* __restrict__ n1,
                                                    float* __restrict__ out){
  __shared__ float r1[256], r2[256], r3[256]; __shared__ int r4[256];
  int tid = threadIdx.x;
  float s1 = 0.f, s2 = 0.f, s3 = 0.f; int pc = 0;
  for (int i = tid; i < NROWS; i += 256){
    float a = ap[i], b = an[i];
    float n12 = an[n1[i]];
    float p12 = ap[p2[i]];
    s1 += fmaxf(a - b, 0.f);
    s2 += fmaxf(a - n12, 0.f);
    s3 += fmaxf(p12 - b, 0.f);
    pc += (b > a) ? 1 : 0;
  }
  r1[tid] = s1; r2[tid] = s2; r3[tid] = s3; r4[tid] = pc;
  __syncthreads();
  for (int s = 128; s > 0; s >>= 1){
    if (tid < s){ r1[tid] += r1[tid + s]; r2[tid] += r2[tid + s]; r3[tid] += r3[tid + s]; r4[tid] += r4[tid + s]; }
    __syncthreads();
  }
  if (tid == 0){
    float inv = 1.f / (float)NROWS;
    out[0] = r1[0] * inv + 0.1f * (r2[0] * inv) + 0.1f * (r3[0] * inv);
    out[1] = (float)r4[0] * inv;
  }
}

extern "C" void kernel_launch(void* const* d_in, const int* in_sizes, int n_in,
                              void* d_out, int out_size, void* d_ws, size_t ws_size,
                              hipStream_t stream){
  const float* inputs = (const float*)d_in[0];
  const int* targets = (const int*)d_in[1];
  float* out = (float*)d_out;
  char* ws = (char*)d_ws;

  u16* phi = (u16*)ws;                                   // 2 MiB packed hi
  u16* plo = (u16*)(ws + (2u << 20));                    // 2 MiB packed lo
  float* sq = (float*)(ws + (4u << 20));                 // 32 KiB
  u64* pos_key = (u64*)(ws + (4u << 20) + (64u << 10));  // 64 KiB
  u64* neg_key = (u64*)(ws + (4u << 20) + (128u << 10)); // 64 KiB
  float* ap = (float*)(ws + (4u << 20) + (192u << 10));
  float* an = (float*)(ws + (4u << 20) + (224u << 10));
  int* p2 = (int*)(ws + (4u << 20) + (256u << 10));
  int* n1 = (int*)(ws + (4u << 20) + (288u << 10));

  hipMemsetAsync(pos_key, 0x00, NROWS * sizeof(u64), stream);
  hipMemsetAsync(neg_key, 0xFF, NROWS * sizeof(u64), stream);

  pack_kernel<<<(NROWS * 16) / 256, 256, 0, stream>>>(inputs, phi, plo, sq);
  dist_kernel<<<64 * 64, 512, 0, stream>>>(phi, plo, sq, targets, out + 2, pos_key, neg_key);
  decode_kernel<<<NROWS / 256, 256, 0, stream>>>(pos_key, neg_key, ap, an, p2, n1);
  final_kernel<<<1, 256, 0, stream>>>(ap, an, p2, n1, out);
}

// Round 8
// 151.350 us; speedup vs baseline: 1.7764x; 1.0985x over previous
//
#include <hip/hip_runtime.h>

#define NROWS 8192
#define DDIM 128

typedef unsigned short u16;
typedef unsigned int u32;
typedef unsigned long long u64;
typedef __attribute__((ext_vector_type(4))) float f32x4;
typedef __attribute__((ext_vector_type(2))) float f32x2;
typedef __attribute__((ext_vector_type(4))) int i32x4;
typedef __attribute__((ext_vector_type(8))) short short8;

__device__ __forceinline__ u16 f32_to_bf16(float f){
  u32 u = __float_as_uint(f);
  u32 r = (u + 0x7FFFu + ((u >> 16) & 1u)) >> 16;
  return (u16)r;
}
__device__ __forceinline__ float bf16_to_f32(u16 h){ return __uint_as_float(((u32)h) << 16); }

// ---------------- kernel 1: split f32 -> bf16 hi/lo (fragment-packed) + sq + key init ----------------
__global__ __launch_bounds__(256) void pack_kernel(const float* __restrict__ in,
                                                   u16* __restrict__ phi, u16* __restrict__ plo,
                                                   float* __restrict__ sq,
                                                   u64* __restrict__ pos_key, u64* __restrict__ neg_key){
  int t = blockIdx.x * 256 + threadIdx.x;
  if (t < NROWS){ pos_key[t] = 0ull; neg_key[t] = 0xFFFFFFFFFFFFFFFFull; }
  int r = t >> 4, s = t & 15;                  // row, 8-elem segment
  const float* src = in + (size_t)r * DDIM + s * 8;
  f32x4 a = *(const f32x4*)(src);
  f32x4 b = *(const f32x4*)(src + 4);
  float x[8] = {a.x, a.y, a.z, a.w, b.x, b.y, b.z, b.w};
  short8 hv, lv;
  float ss = 0.f;
  #pragma unroll
  for (int j = 0; j < 8; ++j){
    u16 h = f32_to_bf16(x[j]);
    u16 l = f32_to_bf16(x[j] - bf16_to_f32(h));
    hv[j] = (short)h; lv[j] = (short)l;
    ss += x[j] * x[j];
  }
  size_t dst = (((size_t)(r >> 4) * 4 + (s >> 2)) * 64 + (s & 3) * 16 + (r & 15)) * 8;
  *(short8*)(phi + dst) = hv;
  *(short8*)(plo + dst) = lv;
  #pragma unroll
  for (int m = 1; m < 16; m <<= 1) ss += __shfl_xor(ss, m, 64);
  if (s == 0) sq[r] = ss;
}

// ---------------- kernel 2: LDS-free MFMA distance, register-double-buffered K loop ----------------
__global__ __launch_bounds__(256, 2) void dist_kernel(
    const u16* __restrict__ phi, const u16* __restrict__ plo,
    const float* __restrict__ sq, const int* __restrict__ tgt,
    float* __restrict__ dist, u64* __restrict__ pos_key, u64* __restrict__ neg_key)
{
  int id = blockIdx.x;
  int swz = (id & 7) * 512 + (id >> 3);
  const int bi = swz >> 6, bj = swz & 63;

  const int tid = threadIdx.x;
  const int w = tid >> 6, lane = tid & 63;
  const int wr = w >> 1, wc = w & 1;           // 2x2 waves, each owns 64x64 output
  const int lr = lane & 15, g = lane >> 4;

  // acc[m][n] = mfma(B_frag, A_frag):
  //   row = bi*128 + wr*64 + m*16 + lr
  //   col = bj*128 + wc*64 + n*16 + g*4 + r
  f32x4 acc[4][4] = {};

  // register double-buffer: buf[parity][m*2 + (0=hi,1=lo)]
  short8 bufA[2][8], bufB[2][8];
  #pragma unroll
  for (int m = 0; m < 4; ++m){
    size_t offA = ((size_t)(((bi * 8 + wr * 4 + m) * 4 + 0) * 64) + lane) * 8;
    bufA[0][m * 2 + 0] = *(const short8*)(phi + offA);
    bufA[0][m * 2 + 1] = *(const short8*)(plo + offA);
    size_t offB = ((size_t)(((bj * 8 + wc * 4 + m) * 4 + 0) * 64) + lane) * 8;
    bufB[0][m * 2 + 0] = *(const short8*)(phi + offB);
    bufB[0][m * 2 + 1] = *(const short8*)(plo + offB);
  }
  #pragma unroll
  for (int kk = 0; kk < 4; ++kk){
    const int cur = kk & 1, nxt = cur ^ 1;     // compile-time after unroll
    if (kk < 3){
      #pragma unroll
      for (int m = 0; m < 4; ++m){
        size_t offA = ((size_t)(((bi * 8 + wr * 4 + m) * 4 + (kk + 1)) * 64) + lane) * 8;
        bufA[nxt][m * 2 + 0] = *(const short8*)(phi + offA);
        bufA[nxt][m * 2 + 1] = *(const short8*)(plo + offA);
        size_t offB = ((size_t)(((bj * 8 + wc * 4 + m) * 4 + (kk + 1)) * 64) + lane) * 8;
        bufB[nxt][m * 2 + 0] = *(const short8*)(phi + offB);
        bufB[nxt][m * 2 + 1] = *(const short8*)(plo + offB);
      }
    }
    #pragma unroll
    for (int m = 0; m < 4; ++m)
      #pragma unroll
      for (int n = 0; n < 4; ++n){
        acc[m][n] = __builtin_amdgcn_mfma_f32_16x16x32_bf16(bufB[cur][n*2+0], bufA[cur][m*2+0], acc[m][n], 0, 0, 0);
        acc[m][n] = __builtin_amdgcn_mfma_f32_16x16x32_bf16(bufB[cur][n*2+1], bufA[cur][m*2+0], acc[m][n], 0, 0, 0);
        acc[m][n] = __builtin_amdgcn_mfma_f32_16x16x32_bf16(bufB[cur][n*2+0], bufA[cur][m*2+1], acc[m][n], 0, 0, 0);
      }
  }

  // ---- epilogue: d2 -> dist (sqrt only feeds stores), mining on d2 (monotone) ----
  f32x4 sqc[4]; i32x4 tcv[4]; int cbase[4];
  #pragma unroll
  for (int n = 0; n < 4; ++n){
    cbase[n] = bj * 128 + wc * 64 + n * 16 + g * 4;
    sqc[n] = *(const f32x4*)(sq + cbase[n]);
    tcv[n] = *(const i32x4*)(tgt + cbase[n]);
  }
  #pragma unroll
  for (int m = 0; m < 4; ++m){
    const int grow = bi * 128 + wr * 64 + m * 16 + lr;
    const float sqr = sq[grow];
    const int tr = tgt[grow];
    float bpv = -1.f, bnv = 3.0e38f; int bpc = 0x7FFFFFFF, bnc = 0x7FFFFFFF;
    float* drow = dist + (size_t)grow * NROWS;
    #pragma unroll
    for (int n = 0; n < 4; ++n){
      f32x4 dd4;
      #pragma unroll
      for (int r = 0; r < 4; ++r){
        float d2 = sqr + sqc[n][r] - 2.f * acc[m][n][r];
        d2 = fminf(fmaxf(d2, 1e-12f), 1e12f);
        dd4[r] = sqrtf(d2);
        if (tr == tcv[n][r]){
          if (d2 > bpv){ bpv = d2; bpc = cbase[n] + r; }
        } else {
          if (d2 < bnv){ bnv = d2; bnc = cbase[n] + r; }
        }
      }
      // dist base is out+2 (8B-aligned) -> two 8B stores
      *(f32x2*)(drow + cbase[n])     = f32x2{dd4.x, dd4.y};
      *(f32x2*)(drow + cbase[n] + 2) = f32x2{dd4.z, dd4.w};
    }
    // reduce across the 4 g-groups (lanes lr, lr+16, lr+32, lr+48 hold the same row)
    #pragma unroll
    for (int msk = 16; msk <= 32; msk <<= 1){
      float ov = __shfl_xor(bpv, msk, 64); int oc = __shfl_xor(bpc, msk, 64);
      if (ov > bpv || (ov == bpv && oc < bpc)){ bpv = ov; bpc = oc; }
      ov = __shfl_xor(bnv, msk, 64); oc = __shfl_xor(bnc, msk, 64);
      if (ov < bnv || (ov == bnv && oc < bnc)){ bnv = ov; bnc = oc; }
    }
    if (g == 0){
      if (bpv >= 0.f)
        atomicMax(&pos_key[grow],
                  ((u64)__float_as_uint(sqrtf(bpv)) << 32) | (u64)(0xFFFFFFFFu - (u32)bpc));
      if (bnv < 3.0e38f)
        atomicMin(&neg_key[grow],
                  ((u64)__float_as_uint(sqrtf(bnv)) << 32) | (u64)(u32)bnc);
    }
  }
}

// ---------------- kernel 3: decode packed keys ----------------
__global__ __launch_bounds__(256) void decode_kernel(const u64* __restrict__ pk, const u64* __restrict__ nk,
                                                     float* __restrict__ ap, float* __restrict__ an,
                                                     int* __restrict__ p2, int* __restrict__ n1){
  int i = blockIdx.x * 256 + threadIdx.x;
  u64 p = pk[i], q = nk[i];
  ap[i] = __uint_as_float((u32)(p >> 32));
  p2[i] = (int)(0xFFFFFFFFu - (u32)(p & 0xFFFFFFFFu));
  an[i] = __uint_as_float((u32)(q >> 32));
  n1[i] = (int)(u32)(q & 0xFFFFFFFFu);
}

// ---------------- kernel 4: gathers + hinge losses + prec (deterministic single block, 1024 thr) ----------------
__global__ __launch_bounds__(1024) void final_kernel(const float* __restrict__ ap, const float* __restrict__ an,
                                                     const int* __restrict__ p2, const int* __restrict__ n1,
                                                     float* __restrict__ out){
  __shared__ float r1[1024], r2[1024], r3[1024]; __shared__ int r4[1024];
  int tid = threadIdx.x;
  float s1 = 0.f, s2 = 0.f, s3 = 0.f; int pc = 0;
  for (int i = tid; i < NROWS; i += 1024){
    float a = ap[i], b = an[i];
    float n12 = an[n1[i]];
    float p12 = ap[p2[i]];
    s1 += fmaxf(a - b, 0.f);
    s2 += fmaxf(a - n12, 0.f);
    s3 += fmaxf(p12 - b, 0.f);
    pc += (b > a) ? 1 : 0;
  }
  r1[tid] = s1; r2[tid] = s2; r3[tid] = s3; r4[tid] = pc;
  __syncthreads();
  for (int s = 512; s > 0; s >>= 1){
    if (tid < s){ r1[tid] += r1[tid + s]; r2[tid] += r2[tid + s]; r3[tid] += r3[tid + s]; r4[tid] += r4[tid + s]; }
    __syncthreads();
  }
  if (tid == 0){
    float inv = 1.f / (float)NROWS;
    out[0] = r1[0] * inv + 0.1f * (r2[0] * inv) + 0.1f * (r3[0] * inv);
    out[1] = (float)r4[0] * inv;
  }
}

extern "C" void kernel_launch(void* const* d_in, const int* in_sizes, int n_in,
                              void* d_out, int out_size, void* d_ws, size_t ws_size,
                              hipStream_t stream){
  const float* inputs = (const float*)d_in[0];
  const int* targets = (const int*)d_in[1];
  float* out = (float*)d_out;
  char* ws = (char*)d_ws;

  u16* phi = (u16*)ws;                                   // 2 MiB packed hi
  u16* plo = (u16*)(ws + (2u << 20));                    // 2 MiB packed lo
  float* sq = (float*)(ws + (4u << 20));                 // 32 KiB
  u64* pos_key = (u64*)(ws + (4u << 20) + (64u << 10));  // 64 KiB
  u64* neg_key = (u64*)(ws + (4u << 20) + (128u << 10)); // 64 KiB
  float* ap = (float*)(ws + (4u << 20) + (192u << 10));
  float* an = (float*)(ws + (4u << 20) + (224u << 10));
  int* p2 = (int*)(ws + (4u << 20) + (256u << 10));
  int* n1 = (int*)(ws + (4u << 20) + (288u << 10));

  pack_kernel<<<(NROWS * 16) / 256, 256, 0, stream>>>(inputs, phi, plo, sq, pos_key, neg_key);
  dist_kernel<<<64 * 64, 256, 0, stream>>>(phi, plo, sq, targets, out + 2, pos_key, neg_key);
  decode_kernel<<<NROWS / 256, 256, 0, stream>>>(pos_key, neg_key, ap, an, p2, n1);
  final_kernel<<<1, 1024, 0, stream>>>(ap, an, p2, n1, out);
}

// Round 9
// 150.732 us; speedup vs baseline: 1.7837x; 1.0041x over previous
//
#include <hip/hip_runtime.h>

#define NROWS 8192
#define DDIM 128

typedef unsigned short u16;
typedef unsigned int u32;
typedef unsigned long long u64;
typedef __attribute__((ext_vector_type(4))) float f32x4;
typedef __attribute__((ext_vector_type(2))) float f32x2;
typedef __attribute__((ext_vector_type(4))) int i32x4;
typedef __attribute__((ext_vector_type(8))) short short8;

__device__ __forceinline__ u16 f32_to_bf16(float f){
  u32 u = __float_as_uint(f);
  u32 r = (u + 0x7FFFu + ((u >> 16) & 1u)) >> 16;
  return (u16)r;
}
__device__ __forceinline__ float bf16_to_f32(u16 h){ return __uint_as_float(((u32)h) << 16); }

// ---------------- kernel 1: split f32 -> bf16 hi/lo (fragment-packed) + sq + key init ----------------
__global__ __launch_bounds__(256) void pack_kernel(const float* __restrict__ in,
                                                   u16* __restrict__ phi, u16* __restrict__ plo,
                                                   float* __restrict__ sq,
                                                   u64* __restrict__ pos_key, u64* __restrict__ neg_key){
  int t = blockIdx.x * 256 + threadIdx.x;
  if (t < NROWS){ pos_key[t] = 0ull; neg_key[t] = 0xFFFFFFFFFFFFFFFFull; }
  int r = t >> 4, s = t & 15;                  // row, 8-elem segment
  const float* src = in + (size_t)r * DDIM + s * 8;
  f32x4 a = *(const f32x4*)(src);
  f32x4 b = *(const f32x4*)(src + 4);
  float x[8] = {a.x, a.y, a.z, a.w, b.x, b.y, b.z, b.w};
  short8 hv, lv;
  float ss = 0.f;
  #pragma unroll
  for (int j = 0; j < 8; ++j){
    u16 h = f32_to_bf16(x[j]);
    u16 l = f32_to_bf16(x[j] - bf16_to_f32(h));
    hv[j] = (short)h; lv[j] = (short)l;
    ss += x[j] * x[j];
  }
  size_t dst = (((size_t)(r >> 4) * 4 + (s >> 2)) * 64 + (s & 3) * 16 + (r & 15)) * 8;
  *(short8*)(phi + dst) = hv;
  *(short8*)(plo + dst) = lv;
  #pragma unroll
  for (int m = 1; m < 16; m <<= 1) ss += __shfl_xor(ss, m, 64);
  if (s == 0) sq[r] = ss;
}

// ---------------- kernel 2: LDS-free MFMA distance, reg-dbuf K loop, 2D-chunked XCD swizzle ----------------
__global__ __launch_bounds__(256, 2) void dist_kernel(
    const u16* __restrict__ phi, const u16* __restrict__ plo,
    const float* __restrict__ sq, const int* __restrict__ tgt,
    float* __restrict__ dist, u64* __restrict__ pos_key, u64* __restrict__ neg_key)
{
  // Each XCD (id%8) owns a 16(bi) x 32(bj) rectangle of the 64x64 block grid:
  // operand working set per XCD = 16 A-panels + 32 B-panels = 3 MB -> L2-resident.
  int id = blockIdx.x;
  int xcd = id & 7, r9 = id >> 3;              // r9 in [0,512)
  int cx = xcd >> 1, cy = xcd & 1;             // 4x2 rectangles
  const int bi = cx * 16 + (r9 >> 5);
  const int bj = cy * 32 + (r9 & 31);

  const int tid = threadIdx.x;
  const int w = tid >> 6, lane = tid & 63;
  const int wr = w >> 1, wc = w & 1;           // 2x2 waves, each owns 64x64 output
  const int lr = lane & 15, g = lane >> 4;

  // acc[m][n] = mfma(B_frag, A_frag):
  //   row = bi*128 + wr*64 + m*16 + lr
  //   col = bj*128 + wc*64 + n*16 + g*4 + r
  f32x4 acc[4][4] = {};

  // register double-buffer: buf[parity][m*2 + (0=hi,1=lo)]
  short8 bufA[2][8], bufB[2][8];
  #pragma unroll
  for (int m = 0; m < 4; ++m){
    size_t offA = ((size_t)(((bi * 8 + wr * 4 + m) * 4 + 0) * 64) + lane) * 8;
    bufA[0][m * 2 + 0] = *(const short8*)(phi + offA);
    bufA[0][m * 2 + 1] = *(const short8*)(plo + offA);
    size_t offB = ((size_t)(((bj * 8 + wc * 4 + m) * 4 + 0) * 64) + lane) * 8;
    bufB[0][m * 2 + 0] = *(const short8*)(phi + offB);
    bufB[0][m * 2 + 1] = *(const short8*)(plo + offB);
  }
  #pragma unroll
  for (int kk = 0; kk < 4; ++kk){
    const int cur = kk & 1, nxt = cur ^ 1;     // compile-time after unroll
    if (kk < 3){
      #pragma unroll
      for (int m = 0; m < 4; ++m){
        size_t offA = ((size_t)(((bi * 8 + wr * 4 + m) * 4 + (kk + 1)) * 64) + lane) * 8;
        bufA[nxt][m * 2 + 0] = *(const short8*)(phi + offA);
        bufA[nxt][m * 2 + 1] = *(const short8*)(plo + offA);
        size_t offB = ((size_t)(((bj * 8 + wc * 4 + m) * 4 + (kk + 1)) * 64) + lane) * 8;
        bufB[nxt][m * 2 + 0] = *(const short8*)(phi + offB);
        bufB[nxt][m * 2 + 1] = *(const short8*)(plo + offB);
      }
    }
    #pragma unroll
    for (int m = 0; m < 4; ++m)
      #pragma unroll
      for (int n = 0; n < 4; ++n){
        acc[m][n] = __builtin_amdgcn_mfma_f32_16x16x32_bf16(bufB[cur][n*2+0], bufA[cur][m*2+0], acc[m][n], 0, 0, 0);
        acc[m][n] = __builtin_amdgcn_mfma_f32_16x16x32_bf16(bufB[cur][n*2+1], bufA[cur][m*2+0], acc[m][n], 0, 0, 0);
        acc[m][n] = __builtin_amdgcn_mfma_f32_16x16x32_bf16(bufB[cur][n*2+0], bufA[cur][m*2+1], acc[m][n], 0, 0, 0);
      }
  }

  // ---- epilogue: d2 -> dist (sqrt only feeds stores), mining on d2 (monotone) ----
  f32x4 sqc[4]; i32x4 tcv[4]; int cbase[4];
  #pragma unroll
  for (int n = 0; n < 4; ++n){
    cbase[n] = bj * 128 + wc * 64 + n * 16 + g * 4;
    sqc[n] = *(const f32x4*)(sq + cbase[n]);
    tcv[n] = *(const i32x4*)(tgt + cbase[n]);
  }
  #pragma unroll
  for (int m = 0; m < 4; ++m){
    const int grow = bi * 128 + wr * 64 + m * 16 + lr;
    const float sqr = sq[grow];
    const int tr = tgt[grow];
    float bpv = -1.f, bnv = 3.0e38f; int bpc = 0x7FFFFFFF, bnc = 0x7FFFFFFF;
    float* drow = dist + (size_t)grow * NROWS;
    #pragma unroll
    for (int n = 0; n < 4; ++n){
      f32x4 dd4;
      #pragma unroll
      for (int r = 0; r < 4; ++r){
        float d2 = sqr + sqc[n][r] - 2.f * acc[m][n][r];
        d2 = fminf(fmaxf(d2, 1e-12f), 1e12f);
        dd4[r] = sqrtf(d2);
        if (tr == tcv[n][r]){
          if (d2 > bpv){ bpv = d2; bpc = cbase[n] + r; }
        } else {
          if (d2 < bnv){ bnv = d2; bnc = cbase[n] + r; }
        }
      }
      // dist base is out+2 (8B-aligned) -> two 8B stores
      *(f32x2*)(drow + cbase[n])     = f32x2{dd4.x, dd4.y};
      *(f32x2*)(drow + cbase[n] + 2) = f32x2{dd4.z, dd4.w};
    }
    // reduce across the 4 g-groups (lanes lr, lr+16, lr+32, lr+48 hold the same row)
    #pragma unroll
    for (int msk = 16; msk <= 32; msk <<= 1){
      float ov = __shfl_xor(bpv, msk, 64); int oc = __shfl_xor(bpc, msk, 64);
      if (ov > bpv || (ov == bpv && oc < bpc)){ bpv = ov; bpc = oc; }
      ov = __shfl_xor(bnv, msk, 64); oc = __shfl_xor(bnc, msk, 64);
      if (ov < bnv || (ov == bnv && oc < bnc)){ bnv = ov; bnc = oc; }
    }
    if (g == 0){
      if (bpv >= 0.f)
        atomicMax(&pos_key[grow],
                  ((u64)__float_as_uint(sqrtf(bpv)) << 32) | (u64)(0xFFFFFFFFu - (u32)bpc));
      if (bnv < 3.0e38f)
        atomicMin(&neg_key[grow],
                  ((u64)__float_as_uint(sqrtf(bnv)) << 32) | (u64)(u32)bnc);
    }
  }
}

// ---------------- kernel 3: decode packed keys ----------------
__global__ __launch_bounds__(256) void decode_kernel(const u64* __restrict__ pk, const u64* __restrict__ nk,
                                                     float* __restrict__ ap, float* __restrict__ an,
                                                     int* __restrict__ p2, int* __restrict__ n1){
  int i = blockIdx.x * 256 + threadIdx.x;
  u64 p = pk[i], q = nk[i];
  ap[i] = __uint_as_float((u32)(p >> 32));
  p2[i] = (int)(0xFFFFFFFFu - (u32)(p & 0xFFFFFFFFu));
  an[i] = __uint_as_float((u32)(q >> 32));
  n1[i] = (int)(u32)(q & 0xFFFFFFFFu);
}

// ---------------- kernel 4: gathers + hinge losses + prec (deterministic single block, 1024 thr) ----------------
__global__ __launch_bounds__(1024) void final_kernel(const float* __restrict__ ap, const float* __restrict__ an,
                                                     const int* __restrict__ p2, const int* __restrict__ n1,
                                                     float* __restrict__ out){
  __shared__ float r1[1024], r2[1024], r3[1024]; __shared__ int r4[1024];
  int tid = threadIdx.x;
  float s1 = 0.f, s2 = 0.f, s3 = 0.f; int pc = 0;
  for (int i = tid; i < NROWS; i += 1024){
    float a = ap[i], b = an[i];
    float n12 = an[n1[i]];
    float p12 = ap[p2[i]];
    s1 += fmaxf(a - b, 0.f);
    s2 += fmaxf(a - n12, 0.f);
    s3 += fmaxf(p12 - b, 0.f);
    pc += (b > a) ? 1 : 0;
  }
  r1[tid] = s1; r2[tid] = s2; r3[tid] = s3; r4[tid] = pc;
  __syncthreads();
  for (int s = 512; s > 0; s >>= 1){
    if (tid < s){ r1[tid] += r1[tid + s]; r2[tid] += r2[tid + s]; r3[tid] += r3[tid + s]; r4[tid] += r4[tid + s]; }
    __syncthreads();
  }
  if (tid == 0){
    float inv = 1.f / (float)NROWS;
    out[0] = r1[0] * inv + 0.1f * (r2[0] * inv) + 0.1f * (r3[0] * inv);
    out[1] = (float)r4[0] * inv;
  }
}

extern "C" void kernel_launch(void* const* d_in, const int* in_sizes, int n_in,
                              void* d_out, int out_size, void* d_ws, size_t ws_size,
                              hipStream_t stream){
  const float* inputs = (const float*)d_in[0];
  const int* targets = (const int*)d_in[1];
  float* out = (float*)d_out;
  char* ws = (char*)d_ws;

  u16* phi = (u16*)ws;                                   // 2 MiB packed hi
  u16* plo = (u16*)(ws + (2u << 20));                    // 2 MiB packed lo
  float* sq = (float*)(ws + (4u << 20));                 // 32 KiB
  u64* pos_key = (u64*)(ws + (4u << 20) + (64u << 10));  // 64 KiB
  u64* neg_key = (u64*)(ws + (4u << 20) + (128u << 10)); // 64 KiB
  float* ap = (float*)(ws + (4u << 20) + (192u << 10));
  float* an = (float*)(ws + (4u << 20) + (224u << 10));
  int* p2 = (int*)(ws + (4u << 20) + (256u << 10));
  int* n1 = (int*)(ws + (4u << 20) + (288u << 10));

  pack_kernel<<<(NROWS * 16) / 256, 256, 0, stream>>>(inputs, phi, plo, sq, pos_key, neg_key);
  dist_kernel<<<64 * 64, 256, 0, stream>>>(phi, plo, sq, targets, out + 2, pos_key, neg_key);
  decode_kernel<<<NROWS / 256, 256, 0, stream>>>(pos_key, neg_key, ap, an, p2, n1);
  final_kernel<<<1, 1024, 0, stream>>>(ap, an, p2, n1, out);
}